// Round 22
// baseline (70.912 us; speedup 1.0000x reference)
//
#include <hip/hip_runtime.h>
#include <stdint.h>

// Causal self-attention: x[8,2048,256] fp32, W_attn[768,256], W_proj[256,256]
// cvtw: weights -> bf16 fragment tiles. qkv_gemm: FUSED x conversion (fp32 ->
// LDS fragment slabs, double-buffered) + GEMM; dense bf16x4 stores, K
// pre-scaled by 1/sqrt(D)*log2e. Flash attn (R19 best): 1024 blocks x 4
// waves, paired chunks x key-halves, fixed-max softmax, additive LDS combine.
// proj GEMM (1024 blocks).
//
// Fragment tile layout (A/B operands): 1KB tiles, off = tile*512 +
// (row&15)*32 + ((c>>3)&3)*8 + (c&7); wave reads 64 lanes x 16B linear.
// Attn fragment layouts (per bh, 131072 elems):
//  Qf: [chunk32][sblk=d>>4][q&31][d&15]
//  Kf: [tile64][sblk=d>>4][key&63][d&15]
//  Vf: [tile64][kblk=(s>>4)&3][d][s&15]

#define BB 8
#define SS 2048
#define CC 256
#define HH 4
#define DD 64

typedef __attribute__((ext_vector_type(8))) __bf16 bf16x8;
typedef __attribute__((ext_vector_type(4))) __bf16 bf16x4;
typedef __attribute__((ext_vector_type(4))) float f32x4;
typedef __attribute__((ext_vector_type(16))) float f32x16;

#define CM 0.18033688011112042f   // (1/sqrt(64)) * log2(e), folded into K

static __device__ __forceinline__ uint32_t cvtpk(float lo, float hi) {
  uint32_t r;
  asm("v_cvt_pk_bf16_f32 %0, %1, %2" : "=v"(r) : "v"(lo), "v"(hi));
  return r;
}
static __device__ __forceinline__ void pl32swap(uint32_t& a, uint32_t& b) {
  asm("v_permlane32_swap_b32 %0, %1" : "+v"(a), "+v"(b));
}
union PU { uint32_t u[4]; bf16x8 v; };

static __device__ __forceinline__ int frag_off(int row, int c8) {
  return ((row >> 4) * 8 + (c8 >> 2)) * 512 + (row & 15) * 32 + (c8 & 3) * 8;
}

// ---------------- weights fp32 -> bf16 fragment tiles (tiny) ----------------
__global__ __launch_bounds__(256) void cvtw_kernel(const float* __restrict__ wa,
                                                   const float* __restrict__ wp,
                                                   __bf16* __restrict__ waf,
                                                   __bf16* __restrict__ wpf) {
  int i = blockIdx.x * 256 + threadIdx.x;      // 0..32767 (8-elem chunks)
  const float* in; __bf16* out;
  if (i < 24576) {
    in = wa + i * 8;
    out = waf + frag_off(i >> 5, i & 31);
  } else {
    int k = i - 24576;
    in = wp + k * 8;
    out = wpf + frag_off(k >> 5, k & 31);
  }
  float4 v0 = ((const float4*)in)[0];
  float4 v1 = ((const float4*)in)[1];
  PU u;
  u.u[0] = cvtpk(v0.x, v0.y);
  u.u[1] = cvtpk(v0.z, v0.w);
  u.u[2] = cvtpk(v1.x, v1.y);
  u.u[3] = cvtpk(v1.z, v1.w);
  *(bf16x8*)out = u.v;
}

// ---------------- QKV GEMM (fused x conversion via LDS slabs) ---------------
// Block: 256 x-rows x 1 otile. Per cb step: 256x32 fp32 slab -> bf16 fragment
// tiles in LDS (linear writes, conflict-free), double-buffered; 16 MFMA/wave.
// otile<8 (Q,K): swapped mfma(W,x) -> dense d stores. otile>=8 (V): mfma(x,W).
__global__ __launch_bounds__(256) void qkv_gemm(const float* __restrict__ x,
                                                const __bf16* __restrict__ waf,
                                                __bf16* __restrict__ qf_,
                                                __bf16* __restrict__ kf_,
                                                __bf16* __restrict__ vf_) {
  __shared__ __bf16 xls[2][8192];        // 2 x 16KB: 16 fragment tiles each
  const int tid = threadIdx.x;
  const int lane = tid & 63;
  const int ln = lane & 15, kg = lane >> 4;
  const int w = tid >> 6;
  const int xs = blockIdx.x & 7;
  const int j = blockIdx.x >> 3;           // 0..95
  const int otile = j % 12;
  const int rg = xs * 8 + j / 12;          // row group (256 rows)
  const int r0b = rg * 256;
  const int ot0 = otile * 4;               // W row-tile
  const int loff = ln * 32 + kg * 8;
  const bool vmode = (otile >= 8);

  // stage cb-slab into LDS fragment tiles; thread t writes chunks t+256*ii
  auto STAGE = [&](int buf, int cb) {
#pragma unroll
    for (int ii = 0; ii < 4; ++ii) {
      int q = ii * 256 + tid;              // 16B chunk id, 0..1023
      int tile = q >> 6, rr = (q >> 2) & 15, c8i = q & 3;
      const float* p = x + (r0b + tile * 16 + rr) * 256 + cb * 32 + c8i * 8;
      float4 v0 = *(const float4*)p;
      float4 v1 = *(const float4*)(p + 4);
      PU u;
      u.u[0] = cvtpk(v0.x, v0.y);
      u.u[1] = cvtpk(v0.z, v0.w);
      u.u[2] = cvtpk(v1.x, v1.y);
      u.u[3] = cvtpk(v1.z, v1.w);
      *(bf16x8*)&xls[buf][q * 8] = u.v;
    }
  };

  f32x4 acc[4][4] = {};
  STAGE(0, 0);
  int cur = 0;
  for (int cb = 0; cb < 8; ++cb) {
    __syncthreads();                       // stage(cur) visible; cur^1 free
    if (cb + 1 < 8) STAGE(cur ^ 1, cb + 1);
    bf16x8 a[4], wv[4];
#pragma unroll
    for (int i = 0; i < 4; ++i)
      a[i] = *(const bf16x8*)&xls[cur][(w * 4 + i) * 512 + loff];
#pragma unroll
    for (int t = 0; t < 4; ++t)
      wv[t] = *(const bf16x8*)(waf + ((ot0 + t) * 8 + cb) * 512 + loff);
    if (vmode) {
#pragma unroll
      for (int i = 0; i < 4; ++i)
#pragma unroll
        for (int t = 0; t < 4; ++t)
          acc[i][t] = __builtin_amdgcn_mfma_f32_16x16x32_bf16(a[i], wv[t], acc[i][t], 0, 0, 0);
    } else {
#pragma unroll
      for (int i = 0; i < 4; ++i)
#pragma unroll
        for (int t = 0; t < 4; ++t)
          acc[i][t] = __builtin_amdgcn_mfma_f32_16x16x32_bf16(wv[t], a[i], acc[i][t], 0, 0, 0);
    }
    cur ^= 1;
  }

  const int r0 = r0b + w * 64;
  const int o0 = ot0 * 16;
  if (!vmode) {
    // D[o-row via kg,r][s-col via ln]; store 4 consecutive d per lane
    const bool isK = (otile >= 4);
    const float sc = isK ? CM : 1.0f;
#pragma unroll
    for (int i = 0; i < 4; ++i) {
      int s = r0 + i * 16 + ln;
      int b = s >> 11, srow = s & 2047;
#pragma unroll
      for (int t = 0; t < 4; ++t) {
        int obase = o0 + t * 16 + kg * 4;     // +r consecutive
        int oo = obase & 255;
        int h = oo >> 6;
        int bh_off = (b * HH + h) * 131072;
        uint32_t lo = cvtpk(acc[i][t][0] * sc, acc[i][t][1] * sc);
        uint32_t hi2 = cvtpk(acc[i][t][2] * sc, acc[i][t][3] * sc);
        uint2 st = { lo, hi2 };
        if (!isK) {
          int off = bh_off + (srow >> 5) * 2048 + t * 512 + (srow & 31) * 16 + kg * 4;
          *(uint2*)(qf_ + off) = st;
        } else {
          int off = bh_off + (srow >> 6) * 4096 + t * 1024 + (srow & 63) * 16 + kg * 4;
          *(uint2*)(kf_ + off) = st;
        }
      }
    }
  } else {
    // D[s-row via kg,r][d-col via ln]; store 4 consecutive s per lane
    const int h = otile - 8;
#pragma unroll
    for (int i = 0; i < 4; ++i) {
      int sg = r0 + i * 16;                   // + kg*4 + r (low bits)
      int b = sg >> 11;
      int bh_off = (b * HH + h) * 131072;
      int sbase = (sg & 2047) + kg * 4;
      int off0 = bh_off + (sbase >> 6) * 4096 + ((sbase >> 4) & 3) * 1024 + (sbase & 15);
#pragma unroll
      for (int t = 0; t < 4; ++t) {
        int d = t * 16 + ln;
        uint32_t lo = cvtpk(acc[i][t][0], acc[i][t][1]);
        uint32_t hi2 = cvtpk(acc[i][t][2], acc[i][t][3]);
        uint2 st = { lo, hi2 };
        *(uint2*)(vf_ + off0 + d * 16) = st;
      }
    }
  }
}

// ---------------- Flash attention (R19: paired chunks, half-tile split) -----
// 1024 blocks x 4 waves. Waves {0,1}/{2,3} -> chunks 2m/2m+1 (key-halves 0/1).
__global__ __launch_bounds__(256, 4) void attn_kernel(const __bf16* __restrict__ qf_,
                                                      const __bf16* __restrict__ kf_,
                                                      const __bf16* __restrict__ vf_,
                                                      __bf16* __restrict__ yf) {
  __shared__ float lsum[2][32];
  __shared__ float lacc[2][64][33];
  const int lane = threadIdx.x & 63;
  const int l31 = lane & 31;
  const int hi = lane >> 5;
  const int w = threadIdx.x >> 6;      // 0..3
  const int kh = w & 1;                // key-half within each 64-key tile
  const int cp = w >> 1;               // chunk-within-pair

  const int bid = blockIdx.x;
  const int xs = bid & 7;              // XCD slot
  const int j = bid >> 3;              // 0..127
  const int bh = xs + 8 * (j & 3);     // 4 bh per XCD
  const int p = j >> 2;                // 0..31 (pair id)
  const int c = (31 - p) * 2 + cp;     // longest pairs first
  const int q0w = c * 32;

  const int loff = l31 * 16 + hi * 8;  // lane offset within any 1KB fragment
  const int koff = kh * 32;            // this wave's key offset within a tile

  const __bf16* Qfb = qf_ + bh * 131072 + c * 2048 + loff;
  const __bf16* Kb  = kf_ + bh * 131072 + loff + kh * 512;   // key-half of each sblk
  const __bf16* Vb  = vf_ + bh * 131072 + loff + kh * 2048;  // kblk pair of this half

  bf16x8 qf[4];
#pragma unroll
  for (int s = 0; s < 4; ++s) qf[s] = *(const bf16x8*)(Qfb + s * 512);

  const int ntot = (q0w + 95) >> 6;    // 64-key tiles; equal within the pair
  const int qrel = l31 + 32 * (c & 1);

  f32x16 acc0 = {}, acc1 = {};
  float lrun = 0.0f;

  for (int kt = 0; kt < ntot; ++kt) {
    bf16x8 ka[4], vfr[2][2];
    {
      const __bf16* Kp = Kb + kt * 4096;
      const __bf16* Vp = Vb + kt * 4096;
#pragma unroll
      for (int s = 0; s < 4; ++s) ka[s] = *(const bf16x8*)(Kp + s * 1024);
      vfr[0][0] = *(const bf16x8*)(Vp);
      vfr[0][1] = *(const bf16x8*)(Vp + 512);
      vfr[1][0] = *(const bf16x8*)(Vp + 1024);
      vfr[1][1] = *(const bf16x8*)(Vp + 1536);
    }

    // QK^T (swapped): s0[r] = S[key = koff + crow(r,hi)][q = l31]
    f32x16 s0 = {};
    __builtin_amdgcn_s_setprio(1);
#pragma unroll
    for (int s = 0; s < 4; ++s) s0 = __builtin_amdgcn_mfma_f32_32x32x16_bf16(ka[s], qf[s], s0, 0, 0, 0);
    __builtin_amdgcn_s_setprio(0);

    if (kt == ntot - 1) {               // diagonal tile: per-lane causal mask
#pragma unroll
      for (int r = 0; r < 16; ++r) {
        int crow = (r & 3) + 8 * (r >> 2) + 4 * hi;
        s0[r] = (crow + koff <= qrel) ? s0[r] : -1e30f;
      }
    }

    // fixed-max softmax: P = exp2(s') (max cancels in the final divide)
#pragma unroll
    for (int r = 0; r < 16; ++r) s0[r] = __builtin_amdgcn_exp2f(s0[r]);

    // per-tile partial sum (transient tree; cross-half shfl deferred)
    {
      float sm[8];
#pragma unroll
      for (int r = 0; r < 8; ++r) sm[r] = s0[r] + s0[r + 8];
#pragma unroll
      for (int st = 4; st > 0; st >>= 1)
#pragma unroll
        for (int r = 0; r < 4; ++r) if (r < st) sm[r] += sm[r + st];
      lrun += sm[0];
    }

    // repack P -> B-fragments
    bf16x8 pf[2];
#pragma unroll
    for (int g = 0; g < 2; ++g) {
      const int o = g * 8;
      uint32_t a = cvtpk(s0[o + 0], s0[o + 1]);
      uint32_t b = cvtpk(s0[o + 4], s0[o + 5]);
      uint32_t c2 = cvtpk(s0[o + 2], s0[o + 3]);
      uint32_t d2 = cvtpk(s0[o + 6], s0[o + 7]);
      pl32swap(a, b);
      pl32swap(c2, d2);
      PU u; u.u[0] = a; u.u[1] = c2; u.u[2] = b; u.u[3] = d2;
      pf[g] = u.v;
    }

    // PV: acc[dh] += V^T[kblk][dh] . P[kblk]
    __builtin_amdgcn_s_setprio(1);
    acc0 = __builtin_amdgcn_mfma_f32_32x32x16_bf16(vfr[0][0], pf[0], acc0, 0, 0, 0);
    acc0 = __builtin_amdgcn_mfma_f32_32x32x16_bf16(vfr[1][0], pf[1], acc0, 0, 0, 0);
    acc1 = __builtin_amdgcn_mfma_f32_32x32x16_bf16(vfr[0][1], pf[0], acc1, 0, 0, 0);
    acc1 = __builtin_amdgcn_mfma_f32_32x32x16_bf16(vfr[1][1], pf[1], acc1, 0, 0, 0);
    __builtin_amdgcn_s_setprio(0);
  }

  // deferred cross-half (hi) combine of the l partial sum
  lrun += __shfl_xor(lrun, 32);

  // ---- combine across the two key-halves (per chunk; additive) ----
  if (kh == 1) {
    if (hi == 0) lsum[cp][l31] = lrun;
#pragma unroll
    for (int r = 0; r < 16; ++r) {
      int d0 = (r & 3) + 8 * (r >> 2) + 4 * hi;
      lacc[cp][d0][l31] = acc0[r];
      lacc[cp][32 + d0][l31] = acc1[r];
    }
  }
  __syncthreads();
  if (kh == 0) {
    float L = lrun + lsum[cp][l31];
    float inv = __builtin_amdgcn_rcpf(L);
    const int b = bh >> 2, h = bh & 3;
    __bf16* ytile = yf + (((b * 128 + c * 2 + (l31 >> 4)) * 8 + h * 2) * 512)
                       + (l31 & 15) * 32 + hi * 4;
#pragma unroll
    for (int g = 0; g < 4; ++g) {
      float a0[4], a1[4];
#pragma unroll
      for (int i2 = 0; i2 < 4; ++i2) {
        int d0 = i2 + 8 * g + 4 * hi;
        a0[i2] = (acc0[g * 4 + i2] + lacc[cp][d0][l31]) * inv;
        a1[i2] = (acc1[g * 4 + i2] + lacc[cp][32 + d0][l31]) * inv;
      }
      uint32_t w0 = cvtpk(a0[0], a0[1]);
      uint32_t w1 = cvtpk(a0[2], a0[3]);
      uint2 st0 = { w0, w1 };
      *(uint2*)(ytile + g * 8) = st0;
      w0 = cvtpk(a1[0], a1[1]);
      w1 = cvtpk(a1[2], a1[3]);
      uint2 st1 = { w0, w1 };
      *(uint2*)(ytile + 512 + g * 8) = st1;   // d+32 -> next col-block tile
    }
  }
}

// ---------------- Proj GEMM: out = y @ W_proj^T (fp32 out) ------------------
// 1024 blocks (4/CU): block = (xcd, otile, row-group of 64); wave = 16 rows.
__global__ __launch_bounds__(256) void proj_gemm(const __bf16* __restrict__ yf,
                                                 const __bf16* __restrict__ wpf,
                                                 float* __restrict__ out) {
  const int lane = threadIdx.x & 63;
  const int ln = lane & 15, kg = lane >> 4;
  const int w = threadIdx.x >> 6;
  const int xs = blockIdx.x & 7;
  const int j = blockIdx.x >> 3;       // 0..127
  const int otile = j & 3;
  const int rt0 = (xs * 32 + (j >> 2)) * 4 + w;   // one 16-row tile per wave
  const int ot0 = otile * 4;
  const int loff = ln * 32 + kg * 8;

  f32x4 acc[4] = {};
  for (int cb = 0; cb < 8; ++cb) {
    bf16x8 a, wv[4];
    a = *(const bf16x8*)(yf + (rt0 * 8 + cb) * 512 + loff);
#pragma unroll
    for (int t = 0; t < 4; ++t)
      wv[t] = *(const bf16x8*)(wpf + ((ot0 + t) * 8 + cb) * 512 + loff);
#pragma unroll
    for (int t = 0; t < 4; ++t)
      acc[t] = __builtin_amdgcn_mfma_f32_16x16x32_bf16(a, wv[t], acc[t], 0, 0, 0);
  }
  const int r0 = rt0 * 16;
  const int o0 = ot0 * 16;
#pragma unroll
  for (int t = 0; t < 4; ++t) {
    int o = o0 + t * 16 + ln;
#pragma unroll
    for (int r = 0; r < 4; ++r) {
      int rout = r0 + kg * 4 + r;
      out[rout * 256 + o] = acc[t][r];
    }
  }
}

extern "C" void kernel_launch(void* const* d_in, const int* in_sizes, int n_in,
                              void* d_out, int out_size, void* d_ws, size_t ws_size,
                              hipStream_t stream) {
  const float* x = (const float*)d_in[0];
  const float* Wa = (const float*)d_in[1];
  const float* Wp = (const float*)d_in[2];

  char* ws = (char*)d_ws;
  __bf16* qfb = (__bf16*)(ws);                    // 8 MiB  Qf
  __bf16* kfb = (__bf16*)(ws + 8388608);          // 8 MiB  Kf (pre-scaled)
  __bf16* vfb = (__bf16*)(ws + 16777216);         // 8 MiB  Vf
  __bf16* yf  = (__bf16*)(ws + 25165824);         // 8 MiB  y fragment tiles
  __bf16* waf = (__bf16*)(ws + 33554432);         // 384 KiB W_attn fragment tiles
  __bf16* wpf = (__bf16*)(ws + 33947648);         // 128 KiB W_proj fragment tiles

  cvtw_kernel<<<128, 256, 0, stream>>>(Wa, Wp, waf, wpf);
  qkv_gemm<<<768, 256, 0, stream>>>(x, waf, qfb, kfb, vfb);
  attn_kernel<<<1024, 256, 0, stream>>>(qfb, kfb, vfb, yf);
  proj_gemm<<<1024, 256, 0, stream>>>(yf, wpf, (float*)d_out);
}

// Round 23
// 67.729 us; speedup vs baseline: 1.0470x; 1.0470x over previous
//
#include <hip/hip_runtime.h>
#include <stdint.h>

// Causal self-attention: x[8,2048,256] fp32, W_attn[768,256], W_proj[256,256]
// cvt->bf16 fragment tiles (cvt3), QKV GEMM (dense 1KB fragment loads, dense
// bf16x4 stores, K pre-scaled by 1/sqrt(D)*log2e), flash attn (R19 best:
// 1024 blocks x 4 waves, paired chunks {2m,2m+1} x key-halves, 32x32x16
// swapped-QK, fixed-max softmax, additive LDS combine), proj GEMM (1024
// blocks, 4/CU).
//
// Fragment tile layout (A/B operands): 1KB tiles, off = tile*512 +
// (row&15)*32 + ((c>>3)&3)*8 + (c&7); wave reads 64 lanes x 16B linear.
// Attn fragment layouts (per bh, 131072 elems):
//  Qf: [chunk32][sblk=d>>4][q&31][d&15]
//  Kf: [tile64][sblk=d>>4][key&63][d&15]
//  Vf: [tile64][kblk=(s>>4)&3][d][s&15]

#define BB 8
#define SS 2048
#define CC 256
#define HH 4
#define DD 64

typedef __attribute__((ext_vector_type(8))) __bf16 bf16x8;
typedef __attribute__((ext_vector_type(4))) __bf16 bf16x4;
typedef __attribute__((ext_vector_type(4))) float f32x4;
typedef __attribute__((ext_vector_type(16))) float f32x16;

#define CM 0.18033688011112042f   // (1/sqrt(64)) * log2(e), folded into K

static __device__ __forceinline__ uint32_t cvtpk(float lo, float hi) {
  uint32_t r;
  asm("v_cvt_pk_bf16_f32 %0, %1, %2" : "=v"(r) : "v"(lo), "v"(hi));
  return r;
}
static __device__ __forceinline__ void pl32swap(uint32_t& a, uint32_t& b) {
  asm("v_permlane32_swap_b32 %0, %1" : "+v"(a), "+v"(b));
}
union PU { uint32_t u[4]; bf16x8 v; };

static __device__ __forceinline__ int frag_off(int row, int c8) {
  return ((row >> 4) * 8 + (c8 >> 2)) * 512 + (row & 15) * 32 + (c8 & 3) * 8;
}

// ---------------- fused fp32 -> bf16 convert into fragment tiles ------------
__global__ __launch_bounds__(256) void cvt3_kernel(const float* __restrict__ x,
                                                   const float* __restrict__ wa,
                                                   const float* __restrict__ wp,
                                                   __bf16* __restrict__ xf,
                                                   __bf16* __restrict__ waf,
                                                   __bf16* __restrict__ wpf) {
  int i = blockIdx.x * blockDim.x + threadIdx.x;
  const float* in; __bf16* out;
  if (i < 524288) {
    in = x + i * 8;
    out = xf + frag_off(i >> 5, i & 31);
  } else if (i < 548864) {
    int j = i - 524288;
    in = wa + j * 8;
    out = waf + frag_off(j >> 5, j & 31);
  } else {
    int k = i - 548864;
    in = wp + k * 8;
    out = wpf + frag_off(k >> 5, k & 31);
  }
  float4 v0 = ((const float4*)in)[0];
  float4 v1 = ((const float4*)in)[1];
  bf16x8 o = { (__bf16)v0.x, (__bf16)v0.y, (__bf16)v0.z, (__bf16)v0.w,
               (__bf16)v1.x, (__bf16)v1.y, (__bf16)v1.z, (__bf16)v1.w };
  *(bf16x8*)out = o;
}

// ---------------- QKV GEMM: qkv = x @ W_attn^T -> Qf/Kf/Vf ----------------
__global__ __launch_bounds__(256) void qkv_gemm(const __bf16* __restrict__ xf,
                                                const __bf16* __restrict__ waf,
                                                __bf16* __restrict__ qf_,
                                                __bf16* __restrict__ kf_,
                                                __bf16* __restrict__ vf_) {
  const int lane = threadIdx.x & 63;
  const int ln = lane & 15, kg = lane >> 4;
  const int w = threadIdx.x >> 6;
  const int xs = blockIdx.x & 7;
  const int j = blockIdx.x >> 3;           // 0..95
  const int otile = j % 12;
  const int rt0 = (xs * 8 + j / 12) * 16 + w * 4;   // x row-tile (16 rows each)
  const int ot0 = otile * 4;               // W row-tile
  const int loff = ln * 32 + kg * 8;
  const bool vmode = (otile >= 8);

  f32x4 acc[4][4] = {};
  for (int cb = 0; cb < 8; ++cb) {
    bf16x8 a[4], wv[4];
#pragma unroll
    for (int i = 0; i < 4; ++i)
      a[i] = *(const bf16x8*)(xf + ((rt0 + i) * 8 + cb) * 512 + loff);
#pragma unroll
    for (int t = 0; t < 4; ++t)
      wv[t] = *(const bf16x8*)(waf + ((ot0 + t) * 8 + cb) * 512 + loff);
    if (vmode) {
#pragma unroll
      for (int i = 0; i < 4; ++i)
#pragma unroll
        for (int t = 0; t < 4; ++t)
          acc[i][t] = __builtin_amdgcn_mfma_f32_16x16x32_bf16(a[i], wv[t], acc[i][t], 0, 0, 0);
    } else {
#pragma unroll
      for (int i = 0; i < 4; ++i)
#pragma unroll
        for (int t = 0; t < 4; ++t)
          acc[i][t] = __builtin_amdgcn_mfma_f32_16x16x32_bf16(wv[t], a[i], acc[i][t], 0, 0, 0);
    }
  }
  const int r0 = rt0 * 16;
  const int o0 = ot0 * 16;
  if (!vmode) {
    const bool isK = (otile >= 4);
    const float sc = isK ? CM : 1.0f;
#pragma unroll
    for (int i = 0; i < 4; ++i) {
      int s = r0 + i * 16 + ln;
      int b = s >> 11, srow = s & 2047;
#pragma unroll
      for (int t = 0; t < 4; ++t) {
        int obase = o0 + t * 16 + kg * 4;     // +r consecutive
        int oo = obase & 255;
        int h = oo >> 6;
        int bh_off = (b * HH + h) * 131072;
        uint32_t lo = cvtpk(acc[i][t][0] * sc, acc[i][t][1] * sc);
        uint32_t hi2 = cvtpk(acc[i][t][2] * sc, acc[i][t][3] * sc);
        uint2 st = { lo, hi2 };
        if (!isK) {
          int off = bh_off + (srow >> 5) * 2048 + t * 512 + (srow & 31) * 16 + kg * 4;
          *(uint2*)(qf_ + off) = st;
        } else {
          int off = bh_off + (srow >> 6) * 4096 + t * 1024 + (srow & 63) * 16 + kg * 4;
          *(uint2*)(kf_ + off) = st;
        }
      }
    }
  } else {
    const int h = otile - 8;
#pragma unroll
    for (int i = 0; i < 4; ++i) {
      int sg = r0 + i * 16;                   // + kg*4 + r (low bits)
      int b = sg >> 11;
      int bh_off = (b * HH + h) * 131072;
      int sbase = (sg & 2047) + kg * 4;
      int off0 = bh_off + (sbase >> 6) * 4096 + ((sbase >> 4) & 3) * 1024 + (sbase & 15);
#pragma unroll
      for (int t = 0; t < 4; ++t) {
        int d = t * 16 + ln;
        uint32_t lo = cvtpk(acc[i][t][0], acc[i][t][1]);
        uint32_t hi2 = cvtpk(acc[i][t][2], acc[i][t][3]);
        uint2 st = { lo, hi2 };
        *(uint2*)(vf_ + off0 + d * 16) = st;
      }
    }
  }
}

// ---------------- Flash attention (R19: paired chunks, half-tile split) -----
// 1024 blocks x 4 waves. Waves {0,1}/{2,3} -> chunks 2m/2m+1 (key-halves 0/1).
__global__ __launch_bounds__(256, 4) void attn_kernel(const __bf16* __restrict__ qf_,
                                                      const __bf16* __restrict__ kf_,
                                                      const __bf16* __restrict__ vf_,
                                                      __bf16* __restrict__ yf) {
  __shared__ float lsum[2][32];
  __shared__ float lacc[2][64][33];
  const int lane = threadIdx.x & 63;
  const int l31 = lane & 31;
  const int hi = lane >> 5;
  const int w = threadIdx.x >> 6;      // 0..3
  const int kh = w & 1;                // key-half within each 64-key tile
  const int cp = w >> 1;               // chunk-within-pair

  const int bid = blockIdx.x;
  const int xs = bid & 7;              // XCD slot
  const int j = bid >> 3;              // 0..127
  const int bh = xs + 8 * (j & 3);     // 4 bh per XCD
  const int p = j >> 2;                // 0..31 (pair id)
  const int c = (31 - p) * 2 + cp;     // longest pairs first
  const int q0w = c * 32;

  const int loff = l31 * 16 + hi * 8;  // lane offset within any 1KB fragment
  const int koff = kh * 32;            // this wave's key offset within a tile

  const __bf16* Qfb = qf_ + bh * 131072 + c * 2048 + loff;
  const __bf16* Kb  = kf_ + bh * 131072 + loff + kh * 512;   // key-half of each sblk
  const __bf16* Vb  = vf_ + bh * 131072 + loff + kh * 2048;  // kblk pair of this half

  bf16x8 qf[4];
#pragma unroll
  for (int s = 0; s < 4; ++s) qf[s] = *(const bf16x8*)(Qfb + s * 512);

  const int ntot = (q0w + 95) >> 6;    // 64-key tiles; equal within the pair
  const int qrel = l31 + 32 * (c & 1);

  f32x16 acc0 = {}, acc1 = {};
  float lrun = 0.0f;

  for (int kt = 0; kt < ntot; ++kt) {
    bf16x8 ka[4], vfr[2][2];
    {
      const __bf16* Kp = Kb + kt * 4096;
      const __bf16* Vp = Vb + kt * 4096;
#pragma unroll
      for (int s = 0; s < 4; ++s) ka[s] = *(const bf16x8*)(Kp + s * 1024);
      vfr[0][0] = *(const bf16x8*)(Vp);
      vfr[0][1] = *(const bf16x8*)(Vp + 512);
      vfr[1][0] = *(const bf16x8*)(Vp + 1024);
      vfr[1][1] = *(const bf16x8*)(Vp + 1536);
    }

    // QK^T (swapped): s0[r] = S[key = koff + crow(r,hi)][q = l31]
    f32x16 s0 = {};
    __builtin_amdgcn_s_setprio(1);
#pragma unroll
    for (int s = 0; s < 4; ++s) s0 = __builtin_amdgcn_mfma_f32_32x32x16_bf16(ka[s], qf[s], s0, 0, 0, 0);
    __builtin_amdgcn_s_setprio(0);

    if (kt == ntot - 1) {               // diagonal tile: per-lane causal mask
#pragma unroll
      for (int r = 0; r < 16; ++r) {
        int crow = (r & 3) + 8 * (r >> 2) + 4 * hi;
        s0[r] = (crow + koff <= qrel) ? s0[r] : -1e30f;
      }
    }

    // fixed-max softmax: P = exp2(s') (max cancels in the final divide)
#pragma unroll
    for (int r = 0; r < 16; ++r) s0[r] = __builtin_amdgcn_exp2f(s0[r]);

    // per-tile partial sum (transient tree; cross-half shfl deferred)
    {
      float sm[8];
#pragma unroll
      for (int r = 0; r < 8; ++r) sm[r] = s0[r] + s0[r + 8];
#pragma unroll
      for (int st = 4; st > 0; st >>= 1)
#pragma unroll
        for (int r = 0; r < 4; ++r) if (r < st) sm[r] += sm[r + st];
      lrun += sm[0];
    }

    // repack P -> B-fragments
    bf16x8 pf[2];
#pragma unroll
    for (int g = 0; g < 2; ++g) {
      const int o = g * 8;
      uint32_t a = cvtpk(s0[o + 0], s0[o + 1]);
      uint32_t b = cvtpk(s0[o + 4], s0[o + 5]);
      uint32_t c2 = cvtpk(s0[o + 2], s0[o + 3]);
      uint32_t d2 = cvtpk(s0[o + 6], s0[o + 7]);
      pl32swap(a, b);
      pl32swap(c2, d2);
      PU u; u.u[0] = a; u.u[1] = c2; u.u[2] = b; u.u[3] = d2;
      pf[g] = u.v;
    }

    // PV: acc[dh] += V^T[kblk][dh] . P[kblk]
    __builtin_amdgcn_s_setprio(1);
    acc0 = __builtin_amdgcn_mfma_f32_32x32x16_bf16(vfr[0][0], pf[0], acc0, 0, 0, 0);
    acc0 = __builtin_amdgcn_mfma_f32_32x32x16_bf16(vfr[1][0], pf[1], acc0, 0, 0, 0);
    acc1 = __builtin_amdgcn_mfma_f32_32x32x16_bf16(vfr[0][1], pf[0], acc1, 0, 0, 0);
    acc1 = __builtin_amdgcn_mfma_f32_32x32x16_bf16(vfr[1][1], pf[1], acc1, 0, 0, 0);
    __builtin_amdgcn_s_setprio(0);
  }

  // deferred cross-half (hi) combine of the l partial sum
  lrun += __shfl_xor(lrun, 32);

  // ---- combine across the two key-halves (per chunk; additive) ----
  if (kh == 1) {
    if (hi == 0) lsum[cp][l31] = lrun;
#pragma unroll
    for (int r = 0; r < 16; ++r) {
      int d0 = (r & 3) + 8 * (r >> 2) + 4 * hi;
      lacc[cp][d0][l31] = acc0[r];
      lacc[cp][32 + d0][l31] = acc1[r];
    }
  }
  __syncthreads();
  if (kh == 0) {
    float L = lrun + lsum[cp][l31];
    float inv = __builtin_amdgcn_rcpf(L);
    const int b = bh >> 2, h = bh & 3;
    __bf16* ytile = yf + (((b * 128 + c * 2 + (l31 >> 4)) * 8 + h * 2) * 512)
                       + (l31 & 15) * 32 + hi * 4;
#pragma unroll
    for (int g = 0; g < 4; ++g) {
      float a0[4], a1[4];
#pragma unroll
      for (int i2 = 0; i2 < 4; ++i2) {
        int d0 = i2 + 8 * g + 4 * hi;
        a0[i2] = (acc0[g * 4 + i2] + lacc[cp][d0][l31]) * inv;
        a1[i2] = (acc1[g * 4 + i2] + lacc[cp][32 + d0][l31]) * inv;
      }
      uint32_t w0 = cvtpk(a0[0], a0[1]);
      uint32_t w1 = cvtpk(a0[2], a0[3]);
      uint2 st0 = { w0, w1 };
      *(uint2*)(ytile + g * 8) = st0;
      w0 = cvtpk(a1[0], a1[1]);
      w1 = cvtpk(a1[2], a1[3]);
      uint2 st1 = { w0, w1 };
      *(uint2*)(ytile + 512 + g * 8) = st1;   // d+32 -> next col-block tile
    }
  }
}

// ---------------- Proj GEMM: out = y @ W_proj^T (fp32 out) ------------------
// 1024 blocks (4/CU): block = (xcd, otile, row-group of 64); wave = 16 rows.
__global__ __launch_bounds__(256) void proj_gemm(const __bf16* __restrict__ yf,
                                                 const __bf16* __restrict__ wpf,
                                                 float* __restrict__ out) {
  const int lane = threadIdx.x & 63;
  const int ln = lane & 15, kg = lane >> 4;
  const int w = threadIdx.x >> 6;
  const int xs = blockIdx.x & 7;
  const int j = blockIdx.x >> 3;       // 0..127
  const int otile = j & 3;
  const int rt0 = (xs * 32 + (j >> 2)) * 4 + w;   // one 16-row tile per wave
  const int ot0 = otile * 4;
  const int loff = ln * 32 + kg * 8;

  f32x4 acc[4] = {};
  for (int cb = 0; cb < 8; ++cb) {
    bf16x8 a, wv[4];
    a = *(const bf16x8*)(yf + (rt0 * 8 + cb) * 512 + loff);
#pragma unroll
    for (int t = 0; t < 4; ++t)
      wv[t] = *(const bf16x8*)(wpf + ((ot0 + t) * 8 + cb) * 512 + loff);
#pragma unroll
    for (int t = 0; t < 4; ++t)
      acc[t] = __builtin_amdgcn_mfma_f32_16x16x32_bf16(a, wv[t], acc[t], 0, 0, 0);
  }
  const int r0 = rt0 * 16;
  const int o0 = ot0 * 16;
#pragma unroll
  for (int t = 0; t < 4; ++t) {
    int o = o0 + t * 16 + ln;
#pragma unroll
    for (int r = 0; r < 4; ++r) {
      int rout = r0 + kg * 4 + r;
      out[rout * 256 + o] = acc[t][r];
    }
  }
}

extern "C" void kernel_launch(void* const* d_in, const int* in_sizes, int n_in,
                              void* d_out, int out_size, void* d_ws, size_t ws_size,
                              hipStream_t stream) {
  const float* x = (const float*)d_in[0];
  const float* Wa = (const float*)d_in[1];
  const float* Wp = (const float*)d_in[2];

  char* ws = (char*)d_ws;
  __bf16* xf  = (__bf16*)(ws);                    // 8 MiB  x fragment tiles
  __bf16* qfb = (__bf16*)(ws + 8388608);          // 8 MiB  Qf
  __bf16* kfb = (__bf16*)(ws + 16777216);         // 8 MiB  Kf (pre-scaled)
  __bf16* vfb = (__bf16*)(ws + 25165824);         // 8 MiB  Vf
  __bf16* yf  = (__bf16*)(ws + 33554432);         // 8 MiB  y fragment tiles
  __bf16* waf = (__bf16*)(ws + 41943040);         // 384 KiB W_attn fragment tiles
  __bf16* wpf = (__bf16*)(ws + 42336256);         // 128 KiB W_proj fragment tiles

  cvt3_kernel<<<2176, 256, 0, stream>>>(x, Wa, Wp, xf, waf, wpf);
  qkv_gemm<<<768, 256, 0, stream>>>(xf, waf, qfb, kfb, vfb);
  attn_kernel<<<1024, 256, 0, stream>>>(qfb, kfb, vfb, yf);
  proj_gemm<<<1024, 256, 0, stream>>>(yf, wpf, (float*)d_out);
}

// Round 24
// 63.224 us; speedup vs baseline: 1.1216x; 1.0713x over previous
//
#include <hip/hip_runtime.h>
#include <stdint.h>

// Causal self-attention: x[8,2048,256] fp32, W_attn[768,256], W_proj[256,256]
// cvt->bf16 fragment tiles, QKV GEMM (dense loads/stores, K pre-scaled),
// flash attn: 1024 blocks x 4 waves on paired chunks {2m,2m+1} x key-halves
// (32-key half-tiles -> small register state, 4 waves/EU), 32x32x16
// swapped-QK, fixed-max softmax, additive LDS combine. proj GEMM (256 blocks,
// 16 MFMA per wave-step). Best-measured composition (R19: 63.3us).
//
// Fragment tile layout (A/B operands): 1KB tiles, off = tile*512 +
// (row&15)*32 + ((c>>3)&3)*8 + (c&7); wave reads 64 lanes x 16B linear.
// Attn fragment layouts (per bh, 131072 elems):
//  Qf: [chunk32][sblk=d>>4][q&31][d&15]
//  Kf: [tile64][sblk=d>>4][key&63][d&15]
//  Vf: [tile64][kblk=(s>>4)&3][d][s&15]

#define BB 8
#define SS 2048
#define CC 256
#define HH 4
#define DD 64

typedef __attribute__((ext_vector_type(8))) __bf16 bf16x8;
typedef __attribute__((ext_vector_type(4))) __bf16 bf16x4;
typedef __attribute__((ext_vector_type(4))) float f32x4;
typedef __attribute__((ext_vector_type(16))) float f32x16;

#define CM 0.18033688011112042f   // (1/sqrt(64)) * log2(e), folded into K

static __device__ __forceinline__ uint32_t cvtpk(float lo, float hi) {
  uint32_t r;
  asm("v_cvt_pk_bf16_f32 %0, %1, %2" : "=v"(r) : "v"(lo), "v"(hi));
  return r;
}
static __device__ __forceinline__ void pl32swap(uint32_t& a, uint32_t& b) {
  asm("v_permlane32_swap_b32 %0, %1" : "+v"(a), "+v"(b));
}
union PU { uint32_t u[4]; bf16x8 v; };

static __device__ __forceinline__ int frag_off(int row, int c8) {
  return ((row >> 4) * 8 + (c8 >> 2)) * 512 + (row & 15) * 32 + (c8 & 3) * 8;
}

// ---------------- fused fp32 -> bf16 convert into fragment tiles ------------
__global__ __launch_bounds__(256) void cvt3_kernel(const float* __restrict__ x,
                                                   const float* __restrict__ wa,
                                                   const float* __restrict__ wp,
                                                   __bf16* __restrict__ xf,
                                                   __bf16* __restrict__ waf,
                                                   __bf16* __restrict__ wpf) {
  int i = blockIdx.x * blockDim.x + threadIdx.x;
  const float* in; __bf16* out;
  if (i < 524288) {
    in = x + i * 8;
    out = xf + frag_off(i >> 5, i & 31);
  } else if (i < 548864) {
    int j = i - 524288;
    in = wa + j * 8;
    out = waf + frag_off(j >> 5, j & 31);
  } else {
    int k = i - 548864;
    in = wp + k * 8;
    out = wpf + frag_off(k >> 5, k & 31);
  }
  float4 v0 = ((const float4*)in)[0];
  float4 v1 = ((const float4*)in)[1];
  bf16x8 o = { (__bf16)v0.x, (__bf16)v0.y, (__bf16)v0.z, (__bf16)v0.w,
               (__bf16)v1.x, (__bf16)v1.y, (__bf16)v1.z, (__bf16)v1.w };
  *(bf16x8*)out = o;
}

// ---------------- QKV GEMM: qkv = x @ W_attn^T -> Qf/Kf/Vf ----------------
__global__ __launch_bounds__(256) void qkv_gemm(const __bf16* __restrict__ xf,
                                                const __bf16* __restrict__ waf,
                                                __bf16* __restrict__ qf_,
                                                __bf16* __restrict__ kf_,
                                                __bf16* __restrict__ vf_) {
  const int lane = threadIdx.x & 63;
  const int ln = lane & 15, kg = lane >> 4;
  const int w = threadIdx.x >> 6;
  const int xs = blockIdx.x & 7;
  const int j = blockIdx.x >> 3;           // 0..95
  const int otile = j % 12;
  const int rt0 = (xs * 8 + j / 12) * 16 + w * 4;   // x row-tile (16 rows each)
  const int ot0 = otile * 4;               // W row-tile
  const int loff = ln * 32 + kg * 8;
  const bool vmode = (otile >= 8);

  f32x4 acc[4][4] = {};
  for (int cb = 0; cb < 8; ++cb) {
    bf16x8 a[4], wv[4];
#pragma unroll
    for (int i = 0; i < 4; ++i)
      a[i] = *(const bf16x8*)(xf + ((rt0 + i) * 8 + cb) * 512 + loff);
#pragma unroll
    for (int t = 0; t < 4; ++t)
      wv[t] = *(const bf16x8*)(waf + ((ot0 + t) * 8 + cb) * 512 + loff);
    if (vmode) {
#pragma unroll
      for (int i = 0; i < 4; ++i)
#pragma unroll
        for (int t = 0; t < 4; ++t)
          acc[i][t] = __builtin_amdgcn_mfma_f32_16x16x32_bf16(a[i], wv[t], acc[i][t], 0, 0, 0);
    } else {
#pragma unroll
      for (int i = 0; i < 4; ++i)
#pragma unroll
        for (int t = 0; t < 4; ++t)
          acc[i][t] = __builtin_amdgcn_mfma_f32_16x16x32_bf16(wv[t], a[i], acc[i][t], 0, 0, 0);
    }
  }
  const int r0 = rt0 * 16;
  const int o0 = ot0 * 16;
  if (!vmode) {
    const bool isK = (otile >= 4);
    const float sc = isK ? CM : 1.0f;
#pragma unroll
    for (int i = 0; i < 4; ++i) {
      int s = r0 + i * 16 + ln;
      int b = s >> 11, srow = s & 2047;
#pragma unroll
      for (int t = 0; t < 4; ++t) {
        int obase = o0 + t * 16 + kg * 4;     // +r consecutive
        int oo = obase & 255;
        int h = oo >> 6;
        int bh_off = (b * HH + h) * 131072;
        uint32_t lo = cvtpk(acc[i][t][0] * sc, acc[i][t][1] * sc);
        uint32_t hi2 = cvtpk(acc[i][t][2] * sc, acc[i][t][3] * sc);
        uint2 st = { lo, hi2 };
        if (!isK) {
          int off = bh_off + (srow >> 5) * 2048 + t * 512 + (srow & 31) * 16 + kg * 4;
          *(uint2*)(qf_ + off) = st;
        } else {
          int off = bh_off + (srow >> 6) * 4096 + t * 1024 + (srow & 63) * 16 + kg * 4;
          *(uint2*)(kf_ + off) = st;
        }
      }
    }
  } else {
    const int h = otile - 8;
#pragma unroll
    for (int i = 0; i < 4; ++i) {
      int sg = r0 + i * 16;                   // + kg*4 + r (low bits)
      int b = sg >> 11;
      int bh_off = (b * HH + h) * 131072;
      int sbase = (sg & 2047) + kg * 4;
      int off0 = bh_off + (sbase >> 6) * 4096 + ((sbase >> 4) & 3) * 1024 + (sbase & 15);
#pragma unroll
      for (int t = 0; t < 4; ++t) {
        int d = t * 16 + ln;
        uint32_t lo = cvtpk(acc[i][t][0], acc[i][t][1]);
        uint32_t hi2 = cvtpk(acc[i][t][2], acc[i][t][3]);
        uint2 st = { lo, hi2 };
        *(uint2*)(vf_ + off0 + d * 16) = st;
      }
    }
  }
}

// ---------------- Flash attention (paired chunks, half-tile split) ----------
// 1024 blocks x 4 waves. Waves {0,1} -> chunk 2m (key-halves 0/1), waves
// {2,3} -> chunk 2m+1. Both chunks' K/V tile streams are byte-identical and
// equal-length -> L1 serves the second pair. Per-wave state = R18's.
__global__ __launch_bounds__(256, 4) void attn_kernel(const __bf16* __restrict__ qf_,
                                                      const __bf16* __restrict__ kf_,
                                                      const __bf16* __restrict__ vf_,
                                                      __bf16* __restrict__ yf) {
  __shared__ float lsum[2][32];
  __shared__ float lacc[2][64][33];
  const int lane = threadIdx.x & 63;
  const int l31 = lane & 31;
  const int hi = lane >> 5;
  const int w = threadIdx.x >> 6;      // 0..3
  const int kh = w & 1;                // key-half within each 64-key tile
  const int cp = w >> 1;               // chunk-within-pair

  const int bid = blockIdx.x;
  const int xs = bid & 7;              // XCD slot
  const int j = bid >> 3;              // 0..127
  const int bh = xs + 8 * (j & 3);     // 4 bh per XCD
  const int p = j >> 2;                // 0..31 (pair id)
  const int c = (31 - p) * 2 + cp;     // longest pairs first
  const int q0w = c * 32;

  const int loff = l31 * 16 + hi * 8;  // lane offset within any 1KB fragment
  const int koff = kh * 32;            // this wave's key offset within a tile

  const __bf16* Qfb = qf_ + bh * 131072 + c * 2048 + loff;
  const __bf16* Kb  = kf_ + bh * 131072 + loff + kh * 512;   // key-half of each sblk
  const __bf16* Vb  = vf_ + bh * 131072 + loff + kh * 2048;  // kblk pair of this half

  bf16x8 qf[4];
#pragma unroll
  for (int s = 0; s < 4; ++s) qf[s] = *(const bf16x8*)(Qfb + s * 512);

  const int ntot = (q0w + 95) >> 6;    // 64-key tiles; equal within the pair
  const int qrel = l31 + 32 * (c & 1);

  f32x16 acc0 = {}, acc1 = {};
  float lrun = 0.0f;                   // this lane's partial sum

  for (int kt = 0; kt < ntot; ++kt) {
    // K half-fragments (4x 1KB) and V fragments (4x 1KB) for this tile
    bf16x8 ka[4], vfr[2][2];
    {
      const __bf16* Kp = Kb + kt * 4096;
      const __bf16* Vp = Vb + kt * 4096;
#pragma unroll
      for (int s = 0; s < 4; ++s) ka[s] = *(const bf16x8*)(Kp + s * 1024);
      vfr[0][0] = *(const bf16x8*)(Vp);
      vfr[0][1] = *(const bf16x8*)(Vp + 512);
      vfr[1][0] = *(const bf16x8*)(Vp + 1024);
      vfr[1][1] = *(const bf16x8*)(Vp + 1536);
    }

    // QK^T (swapped): s0[r] = S[key = koff + crow(r,hi)][q = l31]
    f32x16 s0 = {};
    __builtin_amdgcn_s_setprio(1);
#pragma unroll
    for (int s = 0; s < 4; ++s) s0 = __builtin_amdgcn_mfma_f32_32x32x16_bf16(ka[s], qf[s], s0, 0, 0, 0);
    __builtin_amdgcn_s_setprio(0);

    if (kt == ntot - 1) {               // diagonal tile: per-lane causal mask
#pragma unroll
      for (int r = 0; r < 16; ++r) {
        int crow = (r & 3) + 8 * (r >> 2) + 4 * hi;
        s0[r] = (crow + koff <= qrel) ? s0[r] : -1e30f;
      }
    }

    // fixed-max softmax: P = exp2(s'); scores are O(1) so no overflow, and
    // the max subtraction cancels in the final division by l.
#pragma unroll
    for (int r = 0; r < 16; ++r) s0[r] = __builtin_amdgcn_exp2f(s0[r]);

    // per-tile partial sum (transient tree; cross-half shfl deferred to end)
    {
      float sm[8];
#pragma unroll
      for (int r = 0; r < 8; ++r) sm[r] = s0[r] + s0[r + 8];
#pragma unroll
      for (int st = 4; st > 0; st >>= 1)
#pragma unroll
        for (int r = 0; r < 4; ++r) if (r < st) sm[r] += sm[r + st];
      lrun += sm[0];
    }

    // repack P -> B-fragments: pf[0]=keys koff+0..15, pf[1]=keys koff+16..31
    bf16x8 pf[2];
#pragma unroll
    for (int g = 0; g < 2; ++g) {
      const int o = g * 8;
      uint32_t a = cvtpk(s0[o + 0], s0[o + 1]);
      uint32_t b = cvtpk(s0[o + 4], s0[o + 5]);
      uint32_t c2 = cvtpk(s0[o + 2], s0[o + 3]);
      uint32_t d2 = cvtpk(s0[o + 6], s0[o + 7]);
      pl32swap(a, b);
      pl32swap(c2, d2);
      PU u; u.u[0] = a; u.u[1] = c2; u.u[2] = b; u.u[3] = d2;
      pf[g] = u.v;
    }

    // PV: acc[dh] += V^T[kblk][dh] . P[kblk]
    __builtin_amdgcn_s_setprio(1);
    acc0 = __builtin_amdgcn_mfma_f32_32x32x16_bf16(vfr[0][0], pf[0], acc0, 0, 0, 0);
    acc0 = __builtin_amdgcn_mfma_f32_32x32x16_bf16(vfr[1][0], pf[1], acc0, 0, 0, 0);
    acc1 = __builtin_amdgcn_mfma_f32_32x32x16_bf16(vfr[0][1], pf[0], acc1, 0, 0, 0);
    acc1 = __builtin_amdgcn_mfma_f32_32x32x16_bf16(vfr[1][1], pf[1], acc1, 0, 0, 0);
    __builtin_amdgcn_s_setprio(0);
  }

  // deferred cross-half (hi) combine of the l partial sum (once per wave)
  lrun += __shfl_xor(lrun, 32);

  // ---- combine across the two key-halves (per chunk; additive) ----
  if (kh == 1) {
    if (hi == 0) lsum[cp][l31] = lrun;
#pragma unroll
    for (int r = 0; r < 16; ++r) {
      int d0 = (r & 3) + 8 * (r >> 2) + 4 * hi;
      lacc[cp][d0][l31] = acc0[r];
      lacc[cp][32 + d0][l31] = acc1[r];
    }
  }
  __syncthreads();
  if (kh == 0) {
    float L = lrun + lsum[cp][l31];
    float inv = __builtin_amdgcn_rcpf(L);
    const int b = bh >> 2, h = bh & 3;
    // yf fragment tile: row = b*2048+q, col = h*64+d
    __bf16* ytile = yf + (((b * 128 + c * 2 + (l31 >> 4)) * 8 + h * 2) * 512)
                       + (l31 & 15) * 32 + hi * 4;
#pragma unroll
    for (int g = 0; g < 4; ++g) {
      float a0[4], a1[4];
#pragma unroll
      for (int i2 = 0; i2 < 4; ++i2) {
        int d0 = i2 + 8 * g + 4 * hi;
        a0[i2] = (acc0[g * 4 + i2] + lacc[cp][d0][l31]) * inv;
        a1[i2] = (acc1[g * 4 + i2] + lacc[cp][32 + d0][l31]) * inv;
      }
      uint32_t w0 = cvtpk(a0[0], a0[1]);
      uint32_t w1 = cvtpk(a0[2], a0[3]);
      uint2 st0 = { w0, w1 };
      *(uint2*)(ytile + g * 8) = st0;
      w0 = cvtpk(a1[0], a1[1]);
      w1 = cvtpk(a1[2], a1[3]);
      uint2 st1 = { w0, w1 };
      *(uint2*)(ytile + 512 + g * 8) = st1;   // d+32 -> next col-block tile
    }
  }
}

// ---------------- Proj GEMM: out = y @ W_proj^T (fp32 out) ------------------
__global__ __launch_bounds__(256) void proj_gemm(const __bf16* __restrict__ yf,
                                                 const __bf16* __restrict__ wpf,
                                                 float* __restrict__ out) {
  const int lane = threadIdx.x & 63;
  const int ln = lane & 15, kg = lane >> 4;
  const int w = threadIdx.x >> 6;
  const int xs = blockIdx.x & 7;
  const int j = blockIdx.x >> 3;       // 0..31
  const int otile = j & 3;
  const int rt0 = (xs * 8 + (j >> 2)) * 16 + w * 4;
  const int ot0 = otile * 4;
  const int loff = ln * 32 + kg * 8;

  f32x4 acc[4][4] = {};
  for (int cb = 0; cb < 8; ++cb) {
    bf16x8 a[4], wv[4];
#pragma unroll
    for (int i = 0; i < 4; ++i)
      a[i] = *(const bf16x8*)(yf + ((rt0 + i) * 8 + cb) * 512 + loff);
#pragma unroll
    for (int t = 0; t < 4; ++t)
      wv[t] = *(const bf16x8*)(wpf + ((ot0 + t) * 8 + cb) * 512 + loff);
#pragma unroll
    for (int i = 0; i < 4; ++i)
#pragma unroll
      for (int t = 0; t < 4; ++t)
        acc[i][t] = __builtin_amdgcn_mfma_f32_16x16x32_bf16(a[i], wv[t], acc[i][t], 0, 0, 0);
  }
  const int r0 = rt0 * 16;
  const int o0 = ot0 * 16;
#pragma unroll
  for (int i = 0; i < 4; ++i)
#pragma unroll
    for (int t = 0; t < 4; ++t) {
      int o = o0 + t * 16 + ln;
#pragma unroll
      for (int r = 0; r < 4; ++r) {
        int rout = r0 + i * 16 + kg * 4 + r;
        out[rout * 256 + o] = acc[i][t][r];
      }
    }
}

extern "C" void kernel_launch(void* const* d_in, const int* in_sizes, int n_in,
                              void* d_out, int out_size, void* d_ws, size_t ws_size,
                              hipStream_t stream) {
  const float* x = (const float*)d_in[0];
  const float* Wa = (const float*)d_in[1];
  const float* Wp = (const float*)d_in[2];

  char* ws = (char*)d_ws;
  __bf16* xf  = (__bf16*)(ws);                    // 8 MiB  x fragment tiles
  __bf16* qfb = (__bf16*)(ws + 8388608);          // 8 MiB  Qf
  __bf16* kfb = (__bf16*)(ws + 16777216);         // 8 MiB  Kf (pre-scaled)
  __bf16* vfb = (__bf16*)(ws + 25165824);         // 8 MiB  Vf
  __bf16* yf  = (__bf16*)(ws + 33554432);         // 8 MiB  y fragment tiles
  __bf16* waf = (__bf16*)(ws + 41943040);         // 384 KiB W_attn fragment tiles
  __bf16* wpf = (__bf16*)(ws + 42336256);         // 128 KiB W_proj fragment tiles

  cvt3_kernel<<<2176, 256, 0, stream>>>(x, Wa, Wp, xf, waf, wpf);
  qkv_gemm<<<768, 256, 0, stream>>>(xf, waf, qfb, kfb, vfb);
  attn_kernel<<<1024, 256, 0, stream>>>(qfb, kfb, vfb, yf);
  proj_gemm<<<256, 256, 0, stream>>>(yf, wpf, (float*)d_out);
}